// Round 1
// baseline (203.689 us; speedup 1.0000x reference)
//
#include <hip/hip_runtime.h>

#define NEGV -1e30f

__device__ __forceinline__ float fast_tanh(float x) {
  // tanh(x) = 1 - 2/(exp(2x)+1); saturates to +/-1 correctly for large |x|
  float e = __expf(2.0f * x);
  float r = __builtin_amdgcn_rcpf(e + 1.0f);
  return 1.0f - 2.0f * r;
}

// Fused projection GEMM: rows [0,2048) = inputs@W_in^T + b_in, rows [2048,6144) = memory@W_mem^T
__global__ __launch_bounds__(256) void proj_kernel(
    const float* __restrict__ inputs, const float* __restrict__ memory,
    const float* __restrict__ W_in, const float* __restrict__ b_in,
    const float* __restrict__ W_mem,
    float* __restrict__ in_item, float* __restrict__ mem_item)
{
  const int NIN = 2048;  // B*Ti
  int r = threadIdx.x >> 6;
  int d = threadIdx.x & 63;
  int row = blockIdx.x * 4 + r;
  const float* A; const float* W; float* O; int arow; float bias = 0.f;
  if (row < NIN) { A = inputs; W = W_in;  O = in_item;  arow = row;       bias = b_in[d]; }
  else           { A = memory; W = W_mem; O = mem_item; arow = row - NIN; }
  const float4* a4 = reinterpret_cast<const float4*>(A + (size_t)arow * 256);
  const float4* w4 = reinterpret_cast<const float4*>(W + (size_t)d * 256);
  float acc = 0.f;
  #pragma unroll 8
  for (int k = 0; k < 64; ++k) {
    float4 a = a4[k], w = w4[k];
    acc += a.x * w.x + a.y * w.y + a.z * w.z + a.w * w.w;
  }
  O[(size_t)arow * 64 + d] = acc + bias;
}

// Fused score + softmax + PV. One block per (b, 4 consecutive i rows).
__global__ __launch_bounds__(256) void attn_kernel(
    const float* __restrict__ in_item,   // (B,Ti,64)
    const float* __restrict__ mem_item,  // (B,Tm,64)
    const float* __restrict__ memory,    // (B,Tm,256)
    const int* __restrict__ in_len, const int* __restrict__ mem_len,
    const float* __restrict__ W_final,   // (64)
    float* __restrict__ out)             // (B,Ti,256)
{
  const int Ti = 512, Tm = 1024, DM = 256;
  const int TI = 4, MT = 128;
  int b = blockIdx.y;
  int i0 = blockIdx.x * TI;
  int tid = threadIdx.x;

  __shared__ float4 mt4[16][MT];   // mem_item tile, [d4][m_local], 32 KB, conflict-free
  __shared__ float  q[TI][64];     // 1 KB
  __shared__ float  wf[64];
  __shared__ float  s[TI][Tm];     // scores, 16 KB
  __shared__ float4 pt[Tm];        // normalized probs transposed: pt[m] = (p0,p1,p2,p3), 16 KB

  {
    int ii = tid >> 6, d = tid & 63;
    q[ii][d] = in_item[((size_t)b * Ti + i0 + ii) * 64 + d];
    if (tid < 64) wf[tid] = W_final[tid];
  }
  int ilen = in_len[b], mlen = mem_len[b];

  // ---- score phase ----
  for (int m0 = 0; m0 < Tm; m0 += MT) {
    __syncthreads();   // protect previous tile reads (and initial q/wf writes)
    #pragma unroll
    for (int t = tid; t < 16 * MT; t += 256) {
      int mm = t & (MT - 1), dd4 = t >> 7;
      float4 v = reinterpret_cast<const float4*>(
          mem_item + ((size_t)b * Tm + m0 + mm) * 64)[dd4];
      mt4[dd4][mm] = v;
    }
    __syncthreads();
    for (int e = tid; e < TI * MT; e += 256) {
      int ii = e >> 7, ml = e & (MT - 1);
      int m = m0 + ml;
      const float4* qq = reinterpret_cast<const float4*>(q[ii]);
      const float4* ww = reinterpret_cast<const float4*>(wf);
      float acc = 0.f;
      #pragma unroll
      for (int d4 = 0; d4 < 16; ++d4) {
        float4 mv = mt4[d4][ml];
        float4 qv = qq[d4];
        float4 wv = ww[d4];
        acc += fast_tanh(qv.x + mv.x) * wv.x
             + fast_tanh(qv.y + mv.y) * wv.y
             + fast_tanh(qv.z + mv.z) * wv.z
             + fast_tanh(qv.w + mv.w) * wv.w;
      }
      bool valid = (m < mlen) && ((i0 + ii) < ilen);
      s[ii][m] = valid ? acc : NEGV;
    }
  }
  __syncthreads();

  // ---- softmax: one wave per row ----
  {
    int w = tid >> 6, lane = tid & 63;
    float mx = -3.4e38f;
    for (int k = lane; k < Tm; k += 64) mx = fmaxf(mx, s[w][k]);
    #pragma unroll
    for (int o = 32; o >= 1; o >>= 1) mx = fmaxf(mx, __shfl_xor(mx, o));
    float sum = 0.f;
    for (int k = lane; k < Tm; k += 64) {
      float p = __expf(s[w][k] - mx);
      s[w][k] = p;
      sum += p;
    }
    #pragma unroll
    for (int o = 32; o >= 1; o >>= 1) sum += __shfl_xor(sum, o);
    float inv = 1.0f / sum;
    for (int k = lane; k < Tm; k += 64) {
      reinterpret_cast<float*>(&pt[k])[w] = s[w][k] * inv;
    }
  }
  __syncthreads();

  // ---- PV: out[b, i0+ii, d] = sum_m p[ii][m] * memory[b,m,d]; thread owns d=tid ----
  float acc0 = 0.f, acc1 = 0.f, acc2 = 0.f, acc3 = 0.f;
  const float* memb = memory + (size_t)b * Tm * DM;
  for (int m = 0; m < Tm; ++m) {
    float v = memb[(size_t)m * DM + tid];
    float4 p = pt[m];
    acc0 += p.x * v; acc1 += p.y * v; acc2 += p.z * v; acc3 += p.w * v;
  }
  float* ob = out + ((size_t)b * Ti + i0) * DM + tid;
  ob[0]      = acc0;
  ob[DM]     = acc1;
  ob[2 * DM] = acc2;
  ob[3 * DM] = acc3;
}

extern "C" void kernel_launch(void* const* d_in, const int* in_sizes, int n_in,
                              void* d_out, int out_size, void* d_ws, size_t ws_size,
                              hipStream_t stream) {
  const float* inputs   = (const float*)d_in[0];  // (4,512,256)
  const float* memory   = (const float*)d_in[1];  // (4,1024,256)
  const int*   in_len   = (const int*)  d_in[2];  // (4)
  const int*   mem_len  = (const int*)  d_in[3];  // (4)
  const float* W_in     = (const float*)d_in[4];  // (64,256)
  const float* b_in     = (const float*)d_in[5];  // (64)
  const float* W_mem    = (const float*)d_in[6];  // (64,256)
  const float* W_final  = (const float*)d_in[7];  // (64)
  float* out = (float*)d_out;                     // (4,512,256)

  float* in_item  = (float*)d_ws;                 // (4,512,64)  = 512 KB
  float* mem_item = in_item + 2048 * 64;          // (4,1024,64) = 1 MB

  proj_kernel<<<1536, 256, 0, stream>>>(inputs, memory, W_in, b_in, W_mem,
                                        in_item, mem_item);
  attn_kernel<<<dim3(128, 4), 256, 0, stream>>>(in_item, mem_item, memory,
                                                in_len, mem_len, W_final, out);
}

// Round 2
// 85.797 us; speedup vs baseline: 2.3741x; 2.3741x over previous
//
#include <hip/hip_runtime.h>

__device__ __forceinline__ float fast_tanh(float x) {
  // tanh(x) = 1 - 2/(exp(2x)+1); saturates correctly for large |x|
  float e = __expf(2.0f * x);
  return 1.0f - 2.0f * __builtin_amdgcn_rcpf(e + 1.0f);
}

// ---------------- Projection: rows [0,2048)=inputs@W_in^T+b_in, [2048,6144)=memory@W_mem^T
// Block: 256 threads, 16 rows x 64 cols. W staged in LDS (swizzled, conflict-free b128 reads);
// A rows read as whole-wave-uniform (broadcast) float4 loads.
__global__ __launch_bounds__(256) void proj_kernel(
    const float* __restrict__ inputs, const float* __restrict__ memory,
    const float* __restrict__ W_in, const float* __restrict__ b_in,
    const float* __restrict__ W_mem,
    float* __restrict__ in_item, float* __restrict__ mem_item)
{
  const int NIN = 2048;
  int r0 = blockIdx.x * 16;
  int tid = threadIdx.x;
  __shared__ float4 wlds[64][64];   // [k4][d], swizzled: (k4,d) at wlds[k4][d ^ (k4&7)]

  const float* Wsel; const float* Abase; float* O; int ar0; bool has_bias = (r0 < NIN);
  if (has_bias) { Wsel = W_in;  Abase = inputs; O = in_item;  ar0 = r0; }
  else          { Wsel = W_mem; Abase = memory; O = mem_item; ar0 = r0 - NIN; }

  const float4* Wv = reinterpret_cast<const float4*>(Wsel);
  #pragma unroll
  for (int u = 0; u < 16; ++u) {
    int e = tid + u * 256;          // 0..4095, coalesced read of W row-major
    int k4 = e & 63, dd = e >> 6;
    wlds[k4][dd ^ (k4 & 7)] = Wv[e];
  }
  int d = tid & 63, rg = tid >> 6;  // wave = rg -> whole wave shares rows (broadcast loads)
  float bias = has_bias ? b_in[d] : 0.f;
  __syncthreads();

  const float4* A0 = reinterpret_cast<const float4*>(Abase + (size_t)(ar0 + rg) * 256);
  float acc0 = 0.f, acc1 = 0.f, acc2 = 0.f, acc3 = 0.f;
  #pragma unroll 8
  for (int k4 = 0; k4 < 64; ++k4) {
    float4 w  = wlds[k4][d ^ (k4 & 7)];
    float4 a0 = A0[k4];
    float4 a1 = A0[k4 + 256];       // row +4
    float4 a2 = A0[k4 + 512];       // row +8
    float4 a3 = A0[k4 + 768];       // row +12
    acc0 += a0.x*w.x + a0.y*w.y + a0.z*w.z + a0.w*w.w;
    acc1 += a1.x*w.x + a1.y*w.y + a1.z*w.z + a1.w*w.w;
    acc2 += a2.x*w.x + a2.y*w.y + a2.z*w.z + a2.w*w.w;
    acc3 += a3.x*w.x + a3.y*w.y + a3.z*w.z + a3.w*w.w;
  }
  O[(size_t)(ar0 + rg     ) * 64 + d] = acc0 + bias;
  O[(size_t)(ar0 + rg +  4) * 64 + d] = acc1 + bias;
  O[(size_t)(ar0 + rg +  8) * 64 + d] = acc2 + bias;
  O[(size_t)(ar0 + rg + 12) * 64 + d] = acc3 + bias;
}

// ---------------- Fused score+softmax+PV, flash-style (no max pass: |score| <= sum|wf| <= 8).
// Block: 512 threads (8 waves), TI=4 rows, full Tm loop in MT=128 tiles.
__global__ __launch_bounds__(512, 4) void attn_kernel(
    const float* __restrict__ in_item,   // (B,Ti,64)
    const float* __restrict__ mem_item,  // (B,Tm,64)
    const float* __restrict__ memory,    // (B,Tm,256)
    const int* __restrict__ in_len, const int* __restrict__ mem_len,
    const float* __restrict__ W_final,   // (64)
    float* __restrict__ out)             // (B,Ti,256)
{
  const int Ti = 512, Tm = 1024, DM = 256;
  const int TI = 4, MT = 128, NT = Tm / MT;
  int b = blockIdx.y;
  int i0 = blockIdx.x * TI;
  int tid = threadIdx.x;

  __shared__ float4 mt4[16][MT];   // mem_item tile [d4][m], swizzled cols, 32 KB
  __shared__ float4 pt4[MT];       // p for 4 rows per m, 2 KB
  __shared__ float  q[TI][64];     // 1 KB
  __shared__ float  wf[64];
  __shared__ float4 oacc4[TI][64]; // cross-chunk output reduce, 4 KB
  __shared__ float  red[8];
  __shared__ float  inv_s[TI];

  if (tid < TI * 64) {
    int ii = tid >> 6, dd = tid & 63;
    q[ii][dd] = in_item[((size_t)b * Ti + i0 + ii) * 64 + dd];
  } else if (tid < TI * 64 + 64) {
    wf[tid - TI * 64] = W_final[tid - TI * 64];
  }
  if (tid < TI * 64) {             // zero oacc (256 float4)
    oacc4[tid >> 6][tid & 63] = make_float4(0.f, 0.f, 0.f, 0.f);
  }
  int ilen = in_len[b], mlen = mem_len[b];

  const int s_ii = tid >> 7, s_ml = tid & 127;   // score mapping: 1 entry/thread/tile
  const bool row_valid = (i0 + s_ii) < ilen;
  float psum = 0.f;

  const int dq = tid & 63, chunk = tid >> 6;     // PV mapping: d-quad, m-chunk(=wave)
  float4 a0 = make_float4(0,0,0,0), a1 = a0, a2 = a0, a3 = a0;
  const float* memb = memory + (size_t)b * Tm * DM;

  for (int t = 0; t < NT; ++t) {
    int m0 = t * MT;
    __syncthreads();   // prev tile's mt4/pt4 consumers done (also covers q/wf/oacc init)

    // stage mem_item tile: coalesced 1KB/wave global reads, swizzled LDS writes
    #pragma unroll
    for (int u = 0; u < 4; ++u) {
      int e = tid + u * 512;          // 0..2047
      int dd4 = e & 15, mm = e >> 4;
      float4 v = reinterpret_cast<const float4*>(mem_item)[((size_t)b * Tm + m0 + mm) * 16 + dd4];
      mt4[dd4][mm ^ (dd4 & 7)] = v;
    }
    __syncthreads();

    // score + exp
    {
      const float4* qq = reinterpret_cast<const float4*>(q[s_ii]);
      const float4* ww = reinterpret_cast<const float4*>(wf);
      float sc = 0.f;
      #pragma unroll
      for (int d4 = 0; d4 < 16; ++d4) {
        float4 mv = mt4[d4][s_ml ^ (d4 & 7)];
        float4 qv = qq[d4];
        float4 wv = ww[d4];
        sc += fast_tanh(qv.x + mv.x) * wv.x
            + fast_tanh(qv.y + mv.y) * wv.y
            + fast_tanh(qv.z + mv.z) * wv.z
            + fast_tanh(qv.w + mv.w) * wv.w;
      }
      int m = m0 + s_ml;
      float p = row_valid ? ((m < mlen) ? __expf(sc) : 0.f) : 1.0f;
      reinterpret_cast<float*>(&pt4[s_ml])[s_ii] = p;
      psum += p;
    }
    __syncthreads();

    // PV: thread owns d-quad dq, m in [m0+16*chunk, +16)
    {
      const float* mpb = memb + (size_t)(m0 + chunk * 16) * DM + dq * 4;
      #pragma unroll
      for (int mm = 0; mm < 16; ++mm) {
        float4 v = *reinterpret_cast<const float4*>(mpb + (size_t)mm * DM);
        float4 p = pt4[chunk * 16 + mm];   // wave-uniform -> broadcast
        a0.x += p.x*v.x; a0.y += p.x*v.y; a0.z += p.x*v.z; a0.w += p.x*v.w;
        a1.x += p.y*v.x; a1.y += p.y*v.y; a1.z += p.y*v.z; a1.w += p.y*v.w;
        a2.x += p.z*v.x; a2.y += p.z*v.y; a2.z += p.z*v.z; a2.w += p.z*v.w;
        a3.x += p.w*v.x; a3.y += p.w*v.y; a3.z += p.w*v.z; a3.w += p.w*v.w;
      }
    }
  }
  __syncthreads();

  // row-sum reduce: each wave holds one row's partials (s_ii = tid>>7 wave-uniform)
  {
    float s = psum;
    #pragma unroll
    for (int o = 32; o >= 1; o >>= 1) s += __shfl_xor(s, o);
    if ((tid & 63) == 0) red[tid >> 6] = s;
  }
  __syncthreads();
  if (tid < TI) inv_s[tid] = 1.0f / (red[2 * tid] + red[2 * tid + 1]);

  // cross-chunk output reduce, barrier-phased (no atomics)
  for (int ph = 0; ph < 8; ++ph) {
    if (chunk == ph) {
      float4 t0 = oacc4[0][dq]; t0.x+=a0.x; t0.y+=a0.y; t0.z+=a0.z; t0.w+=a0.w; oacc4[0][dq]=t0;
      float4 t1 = oacc4[1][dq]; t1.x+=a1.x; t1.y+=a1.y; t1.z+=a1.z; t1.w+=a1.w; oacc4[1][dq]=t1;
      float4 t2 = oacc4[2][dq]; t2.x+=a2.x; t2.y+=a2.y; t2.z+=a2.z; t2.w+=a2.w; oacc4[2][dq]=t2;
      float4 t3 = oacc4[3][dq]; t3.x+=a3.x; t3.y+=a3.y; t3.z+=a3.z; t3.w+=a3.w; oacc4[3][dq]=t3;
    }
    __syncthreads();
  }

  // write out, normalized
  #pragma unroll
  for (int u = 0; u < 2; ++u) {
    int e = tid + u * 512;           // 0..1023
    int ii = e >> 8, dd = e & 255;
    float val = reinterpret_cast<const float*>(oacc4[ii])[dd] * inv_s[ii];
    out[((size_t)b * Ti + i0 + ii) * DM + dd] = val;
  }
}

extern "C" void kernel_launch(void* const* d_in, const int* in_sizes, int n_in,
                              void* d_out, int out_size, void* d_ws, size_t ws_size,
                              hipStream_t stream) {
  const float* inputs   = (const float*)d_in[0];  // (4,512,256)
  const float* memory   = (const float*)d_in[1];  // (4,1024,256)
  const int*   in_len   = (const int*)  d_in[2];  // (4)
  const int*   mem_len  = (const int*)  d_in[3];  // (4)
  const float* W_in     = (const float*)d_in[4];  // (64,256)
  const float* b_in     = (const float*)d_in[5];  // (64)
  const float* W_mem    = (const float*)d_in[6];  // (64,256)
  const float* W_final  = (const float*)d_in[7];  // (64)
  float* out = (float*)d_out;                     // (4,512,256)

  float* in_item  = (float*)d_ws;                 // (4,512,64)  = 512 KB
  float* mem_item = in_item + 2048 * 64;          // (4,1024,64) = 1 MB

  proj_kernel<<<384, 256, 0, stream>>>(inputs, memory, W_in, b_in, W_mem,
                                       in_item, mem_item);
  attn_kernel<<<dim3(128, 4), 512, 0, stream>>>(in_item, mem_item, memory,
                                                in_len, mem_len, W_final, out);
}

// Round 3
// 74.406 us; speedup vs baseline: 2.7375x; 1.1531x over previous
//
#include <hip/hip_runtime.h>

#define C2  2.8853900817779268f   // 2*log2(e)
#define L2E 1.4426950408889634f   // log2(e)

// ---------------- Projection (outputs PRE-SCALED by C2 = 2*log2e):
// rows [0,2048): C2*(inputs@W_in^T + b_in) -> in_item ; [2048,6144): C2*(memory@W_mem^T) -> mem_item
__global__ __launch_bounds__(256) void proj_kernel(
    const float* __restrict__ inputs, const float* __restrict__ memory,
    const float* __restrict__ W_in, const float* __restrict__ b_in,
    const float* __restrict__ W_mem,
    float* __restrict__ in_item, float* __restrict__ mem_item)
{
  const int NIN = 2048;
  int r0 = blockIdx.x * 16;
  int tid = threadIdx.x;
  __shared__ float4 wlds[64][64];   // [k4][d], swizzled

  const float* Wsel; const float* Abase; float* O; int ar0; bool has_bias = (r0 < NIN);
  if (has_bias) { Wsel = W_in;  Abase = inputs; O = in_item;  ar0 = r0; }
  else          { Wsel = W_mem; Abase = memory; O = mem_item; ar0 = r0 - NIN; }

  const float4* Wv = reinterpret_cast<const float4*>(Wsel);
  #pragma unroll
  for (int u = 0; u < 16; ++u) {
    int e = tid + u * 256;
    int k4 = e & 63, dd = e >> 6;
    wlds[k4][dd ^ (k4 & 7)] = Wv[e];
  }
  int d = tid & 63, rg = tid >> 6;
  float bias = has_bias ? b_in[d] : 0.f;
  __syncthreads();

  const float4* A0 = reinterpret_cast<const float4*>(Abase + (size_t)(ar0 + rg) * 256);
  float acc0 = 0.f, acc1 = 0.f, acc2 = 0.f, acc3 = 0.f;
  #pragma unroll 8
  for (int k4 = 0; k4 < 64; ++k4) {
    float4 w  = wlds[k4][d ^ (k4 & 7)];
    float4 a0 = A0[k4];
    float4 a1 = A0[k4 + 256];
    float4 a2 = A0[k4 + 512];
    float4 a3 = A0[k4 + 768];
    acc0 += a0.x*w.x + a0.y*w.y + a0.z*w.z + a0.w*w.w;
    acc1 += a1.x*w.x + a1.y*w.y + a1.z*w.z + a1.w*w.w;
    acc2 += a2.x*w.x + a2.y*w.y + a2.z*w.z + a2.w*w.w;
    acc3 += a3.x*w.x + a3.y*w.y + a3.z*w.z + a3.w*w.w;
  }
  O[(size_t)(ar0 + rg     ) * 64 + d] = (acc0 + bias) * C2;
  O[(size_t)(ar0 + rg +  4) * 64 + d] = (acc1 + bias) * C2;
  O[(size_t)(ar0 + rg +  8) * 64 + d] = (acc2 + bias) * C2;
  O[(size_t)(ar0 + rg + 12) * 64 + d] = (acc3 + bias) * C2;
}

// ---------------- Fused score+softmax+PV.
// score = Wsum - 2*S, S = sum_d w_d * rcp(1 + exp2(q'_d + m'_d));  p = exp2(c1 - C2*S)
__global__ __launch_bounds__(512, 4) void attn_kernel(
    const float* __restrict__ in_item,   // (B,Ti,64), pre-scaled
    const float* __restrict__ mem_item,  // (B,Tm,64), pre-scaled
    const float* __restrict__ memory,    // (B,Tm,256)
    const int* __restrict__ in_len, const int* __restrict__ mem_len,
    const float* __restrict__ W_final,   // (64)
    float* __restrict__ out)             // (B,Ti,256)
{
  const int Ti = 512, Tm = 1024, DM = 256;
  const int TI = 4, MT = 128, NT = 8;
  int b = blockIdx.y;
  int i0 = blockIdx.x * TI;
  int tid = threadIdx.x;

  __shared__ float4 smem[16 * 128];  // 32KB: mt4[d4][128] during tiles; osl[8][4][64] in epilogue
  __shared__ float4 pt4[128];        // p transposed: pt4[m] = (p_row0..p_row3)
  __shared__ float  red[8];

  const int s_ii = __builtin_amdgcn_readfirstlane(tid >> 7);  // wave-uniform row index
  const int s_ml = tid & 127;
  const int dq = tid & 63, wv_ = tid >> 6;

  // q row (uniform per wave) -> registers/SGPRs
  float4 qreg[16];
  {
    const float4* qrow = reinterpret_cast<const float4*>(
        in_item + ((size_t)b * Ti + i0 + s_ii) * 64);
    #pragma unroll
    for (int j = 0; j < 16; ++j) qreg[j] = qrow[j];
  }

  float Wsum = 0.f;
  #pragma unroll
  for (int j = 0; j < 64; ++j) Wsum += W_final[j];   // uniform -> s_loads
  const float c1 = L2E * Wsum;
  const float4* Wf4 = reinterpret_cast<const float4*>(W_final);

  int ilen = in_len[b], mlen = mem_len[b];
  const bool row_valid = (i0 + s_ii) < ilen;

  const float4* mem4 = reinterpret_cast<const float4*>(mem_item);
  const float* memb = memory + (size_t)b * Tm * DM;

  float psum = 0.f;
  float4 a0 = make_float4(0,0,0,0), a1 = a0, a2 = a0, a3 = a0;

  // stage tile 0
  #pragma unroll
  for (int u = 0; u < 4; ++u) {
    int e = tid + u * 512, dd4 = e & 15, mm = e >> 4;
    smem[dd4 * 128 + (mm ^ (dd4 & 7))] = mem4[((size_t)b * Tm + mm) * 16 + dd4];
  }
  __syncthreads();

  #pragma unroll 1
  for (int t = 0; t < NT; ++t) {
    int m0 = t * MT;

    // ---- score: 3 VALU + 2 trans per element ----
    float4 S4 = make_float4(0,0,0,0);
    #pragma unroll
    for (int d4 = 0; d4 < 16; ++d4) {
      float4 mv = smem[d4 * 128 + (s_ml ^ (d4 & 7))];
      float4 qv = qreg[d4];
      float4 w  = Wf4[d4];   // uniform -> SGPR
      S4.x = fmaf(w.x, __builtin_amdgcn_rcpf(1.0f + __builtin_amdgcn_exp2f(qv.x + mv.x)), S4.x);
      S4.y = fmaf(w.y, __builtin_amdgcn_rcpf(1.0f + __builtin_amdgcn_exp2f(qv.y + mv.y)), S4.y);
      S4.z = fmaf(w.z, __builtin_amdgcn_rcpf(1.0f + __builtin_amdgcn_exp2f(qv.z + mv.z)), S4.z);
      S4.w = fmaf(w.w, __builtin_amdgcn_rcpf(1.0f + __builtin_amdgcn_exp2f(qv.w + mv.w)), S4.w);
    }
    float S = (S4.x + S4.y) + (S4.z + S4.w);
    int m = m0 + s_ml;
    float p = row_valid ? ((m < mlen) ? __builtin_amdgcn_exp2f(fmaf(-C2, S, c1)) : 0.f)
                        : 1.0f;
    reinterpret_cast<float*>(&pt4[s_ml])[s_ii] = p;
    psum += p;
    __syncthreads();   // pt4 ready; all smem(t) reads done

    // ---- stage next tile (overlaps PV) ----
    if (t + 1 < NT) {
      int m0n = m0 + MT;
      #pragma unroll
      for (int u = 0; u < 4; ++u) {
        int e = tid + u * 512, dd4 = e & 15, mm = e >> 4;
        smem[dd4 * 128 + (mm ^ (dd4 & 7))] = mem4[((size_t)b * Tm + m0n + mm) * 16 + dd4];
      }
    }

    // ---- PV: thread owns d-quad dq, 16 m's ----
    {
      const float* mpb = memb + (size_t)(m0 + wv_ * 16) * DM + dq * 4;
      #pragma unroll
      for (int mm = 0; mm < 16; ++mm) {
        float4 v = *reinterpret_cast<const float4*>(mpb + (size_t)mm * DM);
        float4 pp = pt4[wv_ * 16 + mm];   // wave-uniform broadcast
        a0.x += pp.x*v.x; a0.y += pp.x*v.y; a0.z += pp.x*v.z; a0.w += pp.x*v.w;
        a1.x += pp.y*v.x; a1.y += pp.y*v.y; a1.z += pp.y*v.z; a1.w += pp.y*v.w;
        a2.x += pp.z*v.x; a2.y += pp.z*v.y; a2.z += pp.z*v.z; a2.w += pp.z*v.w;
        a3.x += pp.w*v.x; a3.y += pp.w*v.y; a3.z += pp.w*v.z; a3.w += pp.w*v.w;
      }
    }
    __syncthreads();   // smem(t+1) staged; pt4 consumers done
  }

  // ---- epilogue ----
  {
    float s = psum;
    #pragma unroll
    for (int o = 32; o >= 1; o >>= 1) s += __shfl_xor(s, o);
    if (dq == 0) red[wv_] = s;
  }
  smem[(wv_ * 4 + 0) * 64 + dq] = a0;
  smem[(wv_ * 4 + 1) * 64 + dq] = a1;
  smem[(wv_ * 4 + 2) * 64 + dq] = a2;
  smem[(wv_ * 4 + 3) * 64 + dq] = a3;
  __syncthreads();

  if (tid < 256) {
    int ii = tid >> 6, d2 = tid & 63;
    float4 s = smem[ii * 64 + d2];
    #pragma unroll
    for (int w = 1; w < 8; ++w) {
      float4 v = smem[(w * 4 + ii) * 64 + d2];
      s.x += v.x; s.y += v.y; s.z += v.z; s.w += v.w;
    }
    float inv = __builtin_amdgcn_rcpf(red[2 * ii] + red[2 * ii + 1]);
    s.x *= inv; s.y *= inv; s.z *= inv; s.w *= inv;
    reinterpret_cast<float4*>(out)[((size_t)b * Ti + i0 + ii) * 64 + d2] = s;
  }
}

extern "C" void kernel_launch(void* const* d_in, const int* in_sizes, int n_in,
                              void* d_out, int out_size, void* d_ws, size_t ws_size,
                              hipStream_t stream) {
  const float* inputs   = (const float*)d_in[0];  // (4,512,256)
  const float* memory   = (const float*)d_in[1];  // (4,1024,256)
  const int*   in_len   = (const int*)  d_in[2];  // (4)
  const int*   mem_len  = (const int*)  d_in[3];  // (4)
  const float* W_in     = (const float*)d_in[4];  // (64,256)
  const float* b_in     = (const float*)d_in[5];  // (64)
  const float* W_mem    = (const float*)d_in[6];  // (64,256)
  const float* W_final  = (const float*)d_in[7];  // (64)
  float* out = (float*)d_out;                     // (4,512,256)

  float* in_item  = (float*)d_ws;                 // (4,512,64)
  float* mem_item = in_item + 2048 * 64;          // (4,1024,64)

  proj_kernel<<<384, 256, 0, stream>>>(inputs, memory, W_in, b_in, W_mem,
                                       in_item, mem_item);
  attn_kernel<<<dim3(128, 4), 512, 0, stream>>>(in_item, mem_item, memory,
                                                in_len, mem_len, W_final, out);
}